// Round 4
// baseline (467.255 us; speedup 1.0000x reference)
//
#include <hip/hip_runtime.h>

// ---------- types ----------
typedef __attribute__((ext_vector_type(8))) _Float16 half8;
typedef __attribute__((ext_vector_type(4))) _Float16 half4v;
typedef __attribute__((ext_vector_type(4))) short bshort4;
typedef __attribute__((ext_vector_type(4))) float float4v;

// MFMA wrappers. Host pass chokes on top-level __has_builtin dispatch
// (round-1 failure), so guard with __HIP_DEVICE_COMPILE__.
__device__ __forceinline__ float4v mfma16x16x32_f16(half8 a, half8 b, float4v c) {
#if defined(__HIP_DEVICE_COMPILE__)
#if __has_builtin(__builtin_amdgcn_mfma_f32_16x16x32_f16)
  return __builtin_amdgcn_mfma_f32_16x16x32_f16(a, b, c, 0, 0, 0);
#elif __has_builtin(__builtin_amdgcn_mfma_f32_16x16x32f16)
  return __builtin_amdgcn_mfma_f32_16x16x32f16(a, b, c, 0, 0, 0);
#else
#error "no 16x16x32 f16 mfma"
#endif
#else
  (void)a; (void)b;
  return c;
#endif
}

__device__ __forceinline__ float4v mfma16x16x16_bf16(bshort4 a, bshort4 b, float4v c) {
#if defined(__HIP_DEVICE_COMPILE__)
#if __has_builtin(__builtin_amdgcn_mfma_f32_16x16x16bf16_1k)
  return __builtin_amdgcn_mfma_f32_16x16x16bf16_1k(a, b, c, 0, 0, 0);
#elif __has_builtin(__builtin_amdgcn_mfma_f32_16x16x16_bf16)
  return __builtin_amdgcn_mfma_f32_16x16x16_bf16(a, b, c, 0, 0, 0);
#else
#error "no 16x16x16 bf16 mfma"
#endif
#else
  (void)a; (void)b;
  return c;
#endif
}

__device__ __forceinline__ unsigned short f2h(float f) {
  union { _Float16 h; unsigned short u; } v;
  v.h = (_Float16)f;
  return v.u;
}
__device__ __forceinline__ float h2f(unsigned u) {
  union { unsigned short u; _Float16 h; } v;
  v.u = (unsigned short)u;
  return (float)v.h;
}
__device__ __forceinline__ short f2bf(float f) {
  union { float f; unsigned u; } v; v.f = f;
  unsigned r = v.u + 0x7fffu + ((v.u >> 16) & 1u);  // RNE
  return (short)(r >> 16);
}

// ---------- fp32 -> fp16 convert ----------
__global__ __launch_bounds__(256) void cvt_f32_f16(const float* __restrict__ in,
                                                   unsigned short* __restrict__ out, int n4) {
  int i = blockIdx.x * 256 + threadIdx.x;
  if (i >= n4) return;
  float4 v = ((const float4*)in)[i];
  uint2 o;
  o.x = (unsigned)f2h(v.x) | ((unsigned)f2h(v.y) << 16);
  o.y = (unsigned)f2h(v.z) | ((unsigned)f2h(v.w) << 16);
  ((uint2*)out)[i] = o;
}

// ---------- QKV projection GEMM: C = X @ W[widx]^T + b[widx], fp16 in/out ----------
// grid (4 n-tiles, 96 m-tiles, 3 {q,k,v}); block 256 (4 waves, 2x2 of 64x64)
__global__ __launch_bounds__(256) void gemm_qkv(
    const unsigned short* __restrict__ X,
    const unsigned short* __restrict__ Wq, const unsigned short* __restrict__ Wk,
    const unsigned short* __restrict__ Wv,
    const float* __restrict__ bq, const float* __restrict__ bk, const float* __restrict__ bv,
    unsigned short* __restrict__ Cq, unsigned short* __restrict__ Ck, unsigned short* __restrict__ Cv,
    int wsel_mode, int widx_fixed) {
  const int nt = blockIdx.x, mt = blockIdx.y, z = blockIdx.z;
  const unsigned short* W = (z == 0) ? Wq : ((z == 1) ? Wk : Wv);
  const float* bias = (z == 0) ? bq : ((z == 1) ? bk : bv);
  unsigned short* C = (z == 0) ? Cq : ((z == 1) ? Ck : Cv);
  const int widx = wsel_mode ? (1 + (mt % 3)) : widx_fixed;
  W += (size_t)widx * 512 * 512;
  bias += widx * 512;

  __shared__ __align__(16) unsigned short Xs[128][72];
  __shared__ __align__(16) unsigned short Wt[128][72];
  const int tid = threadIdx.x, lane = tid & 63, w = tid >> 6;
  const int col = lane & 15, grp = lane >> 4;
  const int wm = (w >> 1) * 64, wn = (w & 1) * 64;

  const float4v zero4 = {0.f, 0.f, 0.f, 0.f};
  float4v acc[4][4];
#pragma unroll
  for (int i = 0; i < 4; ++i)
#pragma unroll
    for (int j = 0; j < 4; ++j) acc[i][j] = zero4;

  const int lr = tid >> 3, lc = (tid & 7) * 8;
  for (int k0 = 0; k0 < 512; k0 += 64) {
#pragma unroll
    for (int p = 0; p < 4; ++p) {
      *(half8*)&Xs[lr + 32 * p][lc] =
          *(const half8*)&X[(size_t)(mt * 128 + lr + 32 * p) * 512 + k0 + lc];
      *(half8*)&Wt[lr + 32 * p][lc] =
          *(const half8*)&W[(size_t)(nt * 128 + lr + 32 * p) * 512 + k0 + lc];
    }
    __syncthreads();
#pragma unroll
    for (int kk = 0; kk < 64; kk += 32) {
      half8 af[4], bf[4];
#pragma unroll
      for (int i = 0; i < 4; ++i) af[i] = *(const half8*)&Xs[wm + i * 16 + col][kk + grp * 8];
#pragma unroll
      for (int j = 0; j < 4; ++j) bf[j] = *(const half8*)&Wt[wn + j * 16 + col][kk + grp * 8];
#pragma unroll
      for (int i = 0; i < 4; ++i)
#pragma unroll
        for (int j = 0; j < 4; ++j)
          acc[i][j] = mfma16x16x32_f16(af[i], bf[j], acc[i][j]);
    }
    __syncthreads();
  }
#pragma unroll
  for (int j = 0; j < 4; ++j) {
    const int n = nt * 128 + wn + j * 16 + col;
    const float bj = bias[n];
#pragma unroll
    for (int i = 0; i < 4; ++i)
#pragma unroll
      for (int r = 0; r < 4; ++r) {
        const int m = mt * 128 + wm + i * 16 + grp * 4 + r;
        C[(size_t)m * 512 + n] = f2h(acc[i][j][r] + bj);
      }
  }
}

// ---------- fusion GEMM: diff = Xdiff @ W^T ; out = tl2 + (tl1-tl2)*sigmoid(diff) ----------
__global__ __launch_bounds__(256) void gemm_fusion(
    const unsigned short* __restrict__ X, const unsigned short* __restrict__ Wf,
    const float* __restrict__ tl1, const float* __restrict__ tl2, float* __restrict__ outp) {
  const int nt = blockIdx.x, mt = blockIdx.y;
  __shared__ __align__(16) unsigned short Xs[128][72];
  __shared__ __align__(16) unsigned short Wt[128][72];
  const int tid = threadIdx.x, lane = tid & 63, w = tid >> 6;
  const int col = lane & 15, grp = lane >> 4;
  const int wm = (w >> 1) * 64, wn = (w & 1) * 64;

  const float4v zero4 = {0.f, 0.f, 0.f, 0.f};
  float4v acc[4][4];
#pragma unroll
  for (int i = 0; i < 4; ++i)
#pragma unroll
    for (int j = 0; j < 4; ++j) acc[i][j] = zero4;

  const int lr = tid >> 3, lc = (tid & 7) * 8;
  for (int k0 = 0; k0 < 512; k0 += 64) {
#pragma unroll
    for (int p = 0; p < 4; ++p) {
      *(half8*)&Xs[lr + 32 * p][lc] =
          *(const half8*)&X[(size_t)(mt * 128 + lr + 32 * p) * 512 + k0 + lc];
      *(half8*)&Wt[lr + 32 * p][lc] =
          *(const half8*)&Wf[(size_t)(nt * 128 + lr + 32 * p) * 512 + k0 + lc];
    }
    __syncthreads();
#pragma unroll
    for (int kk = 0; kk < 64; kk += 32) {
      half8 af[4], bf[4];
#pragma unroll
      for (int i = 0; i < 4; ++i) af[i] = *(const half8*)&Xs[wm + i * 16 + col][kk + grp * 8];
#pragma unroll
      for (int j = 0; j < 4; ++j) bf[j] = *(const half8*)&Wt[wn + j * 16 + col][kk + grp * 8];
#pragma unroll
      for (int i = 0; i < 4; ++i)
#pragma unroll
        for (int j = 0; j < 4; ++j)
          acc[i][j] = mfma16x16x32_f16(af[i], bf[j], acc[i][j]);
    }
    __syncthreads();
  }
#pragma unroll
  for (int j = 0; j < 4; ++j) {
    const int n = nt * 128 + wn + j * 16 + col;
#pragma unroll
    for (int i = 0; i < 4; ++i)
#pragma unroll
      for (int r = 0; r < 4; ++r) {
        const int m = mt * 128 + wm + i * 16 + grp * 4 + r;
        const size_t off = (size_t)m * 512 + n;
        const float t1 = tl1[off], t2 = tl2[off];
        const float sg = 1.0f / (1.0f + __expf(-acc[i][j][r]));
        outp[off] = t2 + (t1 - t2) * sg;
      }
  }
}

// ---------- attention, single-S-pass: one 512-thread workgroup per (b,h[,chunk]) ----------
// S[t,s] = sum_dd K[dd,t]*V[dd,s] (×temp). Per t-tile: Z[t] completes within the
// iteration (full s sweep), so one cross-wave reduce + barrier per tt, then
// out[dd,s] += (Q[dd,t]/Z[t]) · exp(S[t,s])  with P,Q' in bf16 (range holds e^30).
template <int T>
__global__ __launch_bounds__(512) void attn_kernel(
    const unsigned short* __restrict__ Qb, const unsigned short* __restrict__ Kb,
    const unsigned short* __restrict__ Vb, const float* __restrict__ temp_base,
    const float* add_src,  // no restrict: may alias outp (in-place tl2)
    float* outp, int chunk_elems,
    const float* __restrict__ tl1_src, unsigned short* __restrict__ diff_out) {
  constexpr int NT = T / 16;           // t-tiles
  constexpr int NSW = (T / 16) / 8;    // s-tiles per wave (8 waves split s)
  constexpr int SLAB = T * 32;
  const int h = blockIdx.x, b = blockIdx.y, cb = blockIdx.z;
  const int base = b * (384 * 512) + cb * chunk_elems + h * SLAB;
  const float tscale = temp_base[cb * 16 + h];

  __shared__ __align__(16) unsigned short KVt[T][40];  // staged V, then K, transposed [t][dd]
  __shared__ float Zp[2][8][16];                       // per-wave Z partials, dbuf by tt parity

  const int tid = threadIdx.x, lane = tid & 63, w = tid >> 6;
  const int col = lane & 15, grp = lane >> 4;

  // --- staging: transpose [32][T] global slab -> KVt[T][40] ---
  auto stage = [&](const unsigned short* src) {
    constexpr int TS = T / 8;  // uint4 slots per dd-row
    constexpr int ITER = 32 * TS / 512;
#pragma unroll
    for (int p = 0; p < ITER; ++p) {
      const int flat = p * 512 + tid;
      const int dd = flat / TS;
      const int t0 = (flat - dd * TS) * 8;
      uint4 vv = *(const uint4*)(src + dd * T + t0);
      unsigned short vu[8] = {(unsigned short)vv.x, (unsigned short)(vv.x >> 16),
                              (unsigned short)vv.y, (unsigned short)(vv.y >> 16),
                              (unsigned short)vv.z, (unsigned short)(vv.z >> 16),
                              (unsigned short)vv.w, (unsigned short)(vv.w >> 16)};
#pragma unroll
      for (int j = 0; j < 8; ++j) KVt[t0 + j][dd] = vu[j];
    }
  };

  stage(Vb + base);
  __syncthreads();
  half8 vfr[NSW];  // this wave's V fragments (strips s-tile = w + si*8)
#pragma unroll
  for (int si = 0; si < NSW; ++si)
    vfr[si] = *(const half8*)&KVt[(w + si * 8) * 16 + col][grp * 8];
  __syncthreads();
  stage(Kb + base);  // reuse same buffer for K
  __syncthreads();

  const float4v zero4 = {0.f, 0.f, 0.f, 0.f};
  const unsigned short* Qsl = Qb + base;
  float4v oacc[NSW][2];
#pragma unroll
  for (int si = 0; si < NSW; ++si) {
    oacc[si][0] = zero4;
    oacc[si][1] = zero4;
  }

  for (int tt = 0; tt < NT; ++tt) {
    const int par = tt & 1;
    half8 kf = *(const half8*)&KVt[tt * 16 + col][grp * 8];
    // S tiles for this wave's strips + exp (fp32, no max needed: e^S fits)
    float pe[NSW][4];
    float z0 = 0.f, z1 = 0.f, z2 = 0.f, z3 = 0.f;
#pragma unroll
    for (int si = 0; si < NSW; ++si) {
      float4v s = mfma16x16x32_f16(kf, vfr[si], zero4);
      pe[si][0] = __expf(s[0] * tscale);
      pe[si][1] = __expf(s[1] * tscale);
      pe[si][2] = __expf(s[2] * tscale);
      pe[si][3] = __expf(s[3] * tscale);
      z0 += pe[si][0];
      z1 += pe[si][1];
      z2 += pe[si][2];
      z3 += pe[si][3];
    }
#pragma unroll
    for (int m = 1; m < 16; m <<= 1) {
      z0 += __shfl_xor(z0, m);
      z1 += __shfl_xor(z1, m);
      z2 += __shfl_xor(z2, m);
      z3 += __shfl_xor(z3, m);
    }
    if (col == 0) {
      const int tb = grp * 4;
      Zp[par][w][tb + 0] = z0;
      Zp[par][w][tb + 1] = z1;
      Zp[par][w][tb + 2] = z2;
      Zp[par][w][tb + 3] = z3;
    }
    __syncthreads();
    // combine 8 wave partials (broadcast reads), reciprocal
    const int tb = grp * 4;
    float zs0 = 0.f, zs1 = 0.f, zs2 = 0.f, zs3 = 0.f;
#pragma unroll
    for (int ww = 0; ww < 8; ++ww) {
      zs0 += Zp[par][ww][tb + 0];
      zs1 += Zp[par][ww][tb + 1];
      zs2 += Zp[par][ww][tb + 2];
      zs3 += Zp[par][ww][tb + 3];
    }
    const float zi0 = 1.0f / zs0, zi1 = 1.0f / zs1, zi2 = 1.0f / zs2, zi3 = 1.0f / zs3;
    // Q fragment scaled by 1/Z -> bf16 A-operand
    const int toff = tt * 16 + tb;
    uint2 q0 = *(const uint2*)(Qsl + col * T + toff);
    uint2 q1 = *(const uint2*)(Qsl + (16 + col) * T + toff);
    bshort4 a0, a1;
    a0[0] = f2bf(h2f(q0.x & 0xffffu) * zi0);
    a0[1] = f2bf(h2f(q0.x >> 16) * zi1);
    a0[2] = f2bf(h2f(q0.y & 0xffffu) * zi2);
    a0[3] = f2bf(h2f(q0.y >> 16) * zi3);
    a1[0] = f2bf(h2f(q1.x & 0xffffu) * zi0);
    a1[1] = f2bf(h2f(q1.x >> 16) * zi1);
    a1[2] = f2bf(h2f(q1.y & 0xffffu) * zi2);
    a1[3] = f2bf(h2f(q1.y >> 16) * zi3);
#pragma unroll
    for (int si = 0; si < NSW; ++si) {
      bshort4 pb;
      pb[0] = f2bf(pe[si][0]);
      pb[1] = f2bf(pe[si][1]);
      pb[2] = f2bf(pe[si][2]);
      pb[3] = f2bf(pe[si][3]);
      oacc[si][0] = mfma16x16x16_bf16(a0, pb, oacc[si][0]);
      oacc[si][1] = mfma16x16x16_bf16(a1, pb, oacc[si][1]);
    }
  }

  // --- epilogue ---
#pragma unroll
  for (int si = 0; si < NSW; ++si) {
    const int s = (w + si * 8) * 16 + col;
#pragma unroll
    for (int m0 = 0; m0 < 2; ++m0) {
#pragma unroll
      for (int r = 0; r < 4; ++r) {
        const int dd = m0 * 16 + grp * 4 + r;
        const int off = base + dd * T + s;
        float v = oacc[si][m0][r];
        if (add_src) v += add_src[off];
        outp[off] = v;
        if (diff_out) diff_out[off] = (unsigned short)f2h(tl1_src[off] - v);
      }
    }
  }
}

// ---------- layernorm over rows of 512: y = (x-mu)*rsqrt(var+eps)*g + b -> fp16 ----------
__global__ __launch_bounds__(256) void ln_kernel(const float* __restrict__ xin,
                                                 const float* __restrict__ g,
                                                 const float* __restrict__ bb,
                                                 unsigned short* __restrict__ y) {
  const int row = blockIdx.x * 4 + (threadIdx.x >> 6);
  const int lane = threadIdx.x & 63;
  const float* xr = xin + (size_t)row * 512;
  float4 v0 = *(const float4*)&xr[lane * 8];
  float4 v1 = *(const float4*)&xr[lane * 8 + 4];
  float s = v0.x + v0.y + v0.z + v0.w + v1.x + v1.y + v1.z + v1.w;
  float q = v0.x * v0.x + v0.y * v0.y + v0.z * v0.z + v0.w * v0.w +
            v1.x * v1.x + v1.y * v1.y + v1.z * v1.z + v1.w * v1.w;
#pragma unroll
  for (int m = 1; m < 64; m <<= 1) {
    s += __shfl_xor(s, m);
    q += __shfl_xor(q, m);
  }
  const float mean = s * (1.0f / 512.0f);
  const float var = q * (1.0f / 512.0f) - mean * mean;
  const float rs = rsqrtf(var + 1e-5f);
  float4 g0 = *(const float4*)&g[lane * 8];
  float4 g1 = *(const float4*)&g[lane * 8 + 4];
  float4 b0 = *(const float4*)&bb[lane * 8];
  float4 b1 = *(const float4*)&bb[lane * 8 + 4];
  uint4 o;
  o.x = (unsigned)f2h((v0.x - mean) * rs * g0.x + b0.x) |
        ((unsigned)f2h((v0.y - mean) * rs * g0.y + b0.y) << 16);
  o.y = (unsigned)f2h((v0.z - mean) * rs * g0.z + b0.z) |
        ((unsigned)f2h((v0.w - mean) * rs * g0.w + b0.w) << 16);
  o.z = (unsigned)f2h((v1.x - mean) * rs * g1.x + b1.x) |
        ((unsigned)f2h((v1.y - mean) * rs * g1.y + b1.y) << 16);
  o.w = (unsigned)f2h((v1.z - mean) * rs * g1.z + b1.z) |
        ((unsigned)f2h((v1.w - mean) * rs * g1.w + b1.w) << 16);
  *(uint4*)&y[(size_t)row * 512 + lane * 8] = o;
}

// ---------- launch ----------
extern "C" void kernel_launch(void* const* d_in, const int* in_sizes, int n_in,
                              void* d_out, int out_size, void* d_ws, size_t ws_size,
                              hipStream_t stream) {
  const float* x = (const float*)d_in[0];
  const float* qw = (const float*)d_in[1];
  const float* qb = (const float*)d_in[2];
  const float* kw = (const float*)d_in[3];
  const float* kb = (const float*)d_in[4];
  const float* vw = (const float*)d_in[5];
  const float* vb = (const float*)d_in[6];
  const float* temp = (const float*)d_in[7];
  const float* ln_g = (const float*)d_in[8];
  const float* ln_b = (const float*)d_in[9];
  const float* fus_w = (const float*)d_in[10];
  // fus_b (d_in[11]) cancels in the 2-way softmax; num_heads (d_in[12]) fixed at 16
  float* out = (float*)d_out;

  const size_t NE = (size_t)32 * 384 * 512;  // 6291456
  const size_t WE = (size_t)5 * 512 * 512;   // 1310720

  char* p = (char*)d_ws;
  auto alloc = [&](size_t bytes) {
    char* r = p;
    p += (bytes + 255) & ~(size_t)255;
    return r;
  };
  unsigned short* xb = (unsigned short*)alloc(NE * 2);
  unsigned short* wqb = (unsigned short*)alloc(WE * 2);
  unsigned short* wkb = (unsigned short*)alloc(WE * 2);
  unsigned short* wvb = (unsigned short*)alloc(WE * 2);
  unsigned short* fwb = (unsigned short*)alloc((size_t)512 * 512 * 2);
  unsigned short* Qb = (unsigned short*)alloc(NE * 2);
  unsigned short* Kb = (unsigned short*)alloc(NE * 2);
  unsigned short* Vb = (unsigned short*)alloc(NE * 2);
  float* xres = (float*)alloc(NE * 4);  // x_ , later tl2 (in place)
  float* tl1 = (float*)alloc(NE * 4);
  unsigned short* yb = (unsigned short*)alloc(NE * 2);  // LN output, later diff (fp16)

  // converts
  cvt_f32_f16<<<(int)((NE / 4 + 255) / 256), 256, 0, stream>>>(x, xb, (int)(NE / 4));
  cvt_f32_f16<<<(int)((WE / 4 + 255) / 256), 256, 0, stream>>>(qw, wqb, (int)(WE / 4));
  cvt_f32_f16<<<(int)((WE / 4 + 255) / 256), 256, 0, stream>>>(kw, wkb, (int)(WE / 4));
  cvt_f32_f16<<<(int)((WE / 4 + 255) / 256), 256, 0, stream>>>(vw, wvb, (int)(WE / 4));
  cvt_f32_f16<<<256, 256, 0, stream>>>(fus_w, fwb, 512 * 512 / 4);

  // block 0 projections + attention -> x_ (xres)
  gemm_qkv<<<dim3(4, 96, 3), 256, 0, stream>>>(xb, wqb, wkb, wvb, qb, kb, vb, Qb, Kb, Vb, 0, 0);
  attn_kernel<384><<<dim3(16, 32, 1), 512, 0, stream>>>(Qb, Kb, Vb, temp, nullptr, xres, 0,
                                                        nullptr, nullptr);
  // blocks 1-3 (chunked) projections + attention -> tl1 = concat + x_
  gemm_qkv<<<dim3(4, 96, 3), 256, 0, stream>>>(xb, wqb, wkb, wvb, qb, kb, vb, Qb, Kb, Vb, 1, 0);
  attn_kernel<128><<<dim3(16, 32, 3), 512, 0, stream>>>(Qb, Kb, Vb, temp + 16, xres, tl1,
                                                        128 * 512, nullptr, nullptr);
  // layernorm -> y (fp16)
  ln_kernel<<<12288 / 4, 256, 0, stream>>>(tl1, ln_g, ln_b, yb);
  // block 4 projections + attention -> tl2 = out + x_ (in-place into xres), diff -> yb
  gemm_qkv<<<dim3(4, 96, 3), 256, 0, stream>>>(yb, wqb, wkb, wvb, qb, kb, vb, Qb, Kb, Vb, 0, 4);
  attn_kernel<384><<<dim3(16, 32, 1), 512, 0, stream>>>(Qb, Kb, Vb, temp + 64, xres, xres, 0,
                                                        tl1, yb);
  // fusion: out = tl2 + (tl1-tl2)*sigmoid((tl1-tl2)@fus_w^T)
  gemm_fusion<<<dim3(4, 96, 1), 256, 0, stream>>>(yb, fwb, tl1, xres, out);

  (void)in_sizes; (void)n_in; (void)out_size; (void)ws_size;
}

// Round 5
// 418.461 us; speedup vs baseline: 1.1166x; 1.1166x over previous
//
#include <hip/hip_runtime.h>

// ---------- types ----------
typedef __attribute__((ext_vector_type(8))) _Float16 half8;
typedef __attribute__((ext_vector_type(4))) _Float16 half4v;
typedef __attribute__((ext_vector_type(4))) float float4v;

// MFMA wrappers. Host pass chokes on top-level __has_builtin dispatch
// (round-1 failure), so guard with __HIP_DEVICE_COMPILE__.
__device__ __forceinline__ float4v mfma16x16x32_f16(half8 a, half8 b, float4v c) {
#if defined(__HIP_DEVICE_COMPILE__)
#if __has_builtin(__builtin_amdgcn_mfma_f32_16x16x32_f16)
  return __builtin_amdgcn_mfma_f32_16x16x32_f16(a, b, c, 0, 0, 0);
#elif __has_builtin(__builtin_amdgcn_mfma_f32_16x16x32f16)
  return __builtin_amdgcn_mfma_f32_16x16x32f16(a, b, c, 0, 0, 0);
#else
#error "no 16x16x32 f16 mfma"
#endif
#else
  (void)a; (void)b;
  return c;
#endif
}

__device__ __forceinline__ float4v mfma16x16x16_f16(half4v a, half4v b, float4v c) {
#if defined(__HIP_DEVICE_COMPILE__)
#if __has_builtin(__builtin_amdgcn_mfma_f32_16x16x16f16)
  return __builtin_amdgcn_mfma_f32_16x16x16f16(a, b, c, 0, 0, 0);
#elif __has_builtin(__builtin_amdgcn_mfma_f32_16x16x16_f16)
  return __builtin_amdgcn_mfma_f32_16x16x16_f16(a, b, c, 0, 0, 0);
#else
#error "no 16x16x16 f16 mfma"
#endif
#else
  (void)a; (void)b;
  return c;
#endif
}

__device__ __forceinline__ unsigned short f2h(float f) {
  union { _Float16 h; unsigned short u; } v;
  v.h = (_Float16)f;
  return v.u;
}

// ---------- fp32 -> fp16 convert ----------
__global__ __launch_bounds__(256) void cvt_f32_f16(const float* __restrict__ in,
                                                   unsigned short* __restrict__ out, int n4) {
  int i = blockIdx.x * 256 + threadIdx.x;
  if (i >= n4) return;
  float4 v = ((const float4*)in)[i];
  uint2 o;
  o.x = (unsigned)f2h(v.x) | ((unsigned)f2h(v.y) << 16);
  o.y = (unsigned)f2h(v.z) | ((unsigned)f2h(v.w) << 16);
  ((uint2*)out)[i] = o;
}

// ---------- QKV projection GEMM: C = X @ W[widx]^T + b[widx], fp16 in/out ----------
__global__ __launch_bounds__(256) void gemm_qkv(
    const unsigned short* __restrict__ X,
    const unsigned short* __restrict__ Wq, const unsigned short* __restrict__ Wk,
    const unsigned short* __restrict__ Wv,
    const float* __restrict__ bq, const float* __restrict__ bk, const float* __restrict__ bv,
    unsigned short* __restrict__ Cq, unsigned short* __restrict__ Ck, unsigned short* __restrict__ Cv,
    int wsel_mode, int widx_fixed) {
  const int nt = blockIdx.x, mt = blockIdx.y, z = blockIdx.z;
  const unsigned short* W = (z == 0) ? Wq : ((z == 1) ? Wk : Wv);
  const float* bias = (z == 0) ? bq : ((z == 1) ? bk : bv);
  unsigned short* C = (z == 0) ? Cq : ((z == 1) ? Ck : Cv);
  const int widx = wsel_mode ? (1 + (mt % 3)) : widx_fixed;
  W += (size_t)widx * 512 * 512;
  bias += widx * 512;

  __shared__ __align__(16) unsigned short Xs[128][72];
  __shared__ __align__(16) unsigned short Wt[128][72];
  const int tid = threadIdx.x, lane = tid & 63, w = tid >> 6;
  const int col = lane & 15, grp = lane >> 4;
  const int wm = (w >> 1) * 64, wn = (w & 1) * 64;

  const float4v zero4 = {0.f, 0.f, 0.f, 0.f};
  float4v acc[4][4];
#pragma unroll
  for (int i = 0; i < 4; ++i)
#pragma unroll
    for (int j = 0; j < 4; ++j) acc[i][j] = zero4;

  const int lr = tid >> 3, lc = (tid & 7) * 8;
  for (int k0 = 0; k0 < 512; k0 += 64) {
#pragma unroll
    for (int p = 0; p < 4; ++p) {
      *(half8*)&Xs[lr + 32 * p][lc] =
          *(const half8*)&X[(size_t)(mt * 128 + lr + 32 * p) * 512 + k0 + lc];
      *(half8*)&Wt[lr + 32 * p][lc] =
          *(const half8*)&W[(size_t)(nt * 128 + lr + 32 * p) * 512 + k0 + lc];
    }
    __syncthreads();
#pragma unroll
    for (int kk = 0; kk < 64; kk += 32) {
      half8 af[4], bf[4];
#pragma unroll
      for (int i = 0; i < 4; ++i) af[i] = *(const half8*)&Xs[wm + i * 16 + col][kk + grp * 8];
#pragma unroll
      for (int j = 0; j < 4; ++j) bf[j] = *(const half8*)&Wt[wn + j * 16 + col][kk + grp * 8];
#pragma unroll
      for (int i = 0; i < 4; ++i)
#pragma unroll
        for (int j = 0; j < 4; ++j)
          acc[i][j] = mfma16x16x32_f16(af[i], bf[j], acc[i][j]);
    }
    __syncthreads();
  }
#pragma unroll
  for (int j = 0; j < 4; ++j) {
    const int n = nt * 128 + wn + j * 16 + col;
    const float bj = bias[n];
#pragma unroll
    for (int i = 0; i < 4; ++i)
#pragma unroll
      for (int r = 0; r < 4; ++r) {
        const int m = mt * 128 + wm + i * 16 + grp * 4 + r;
        C[(size_t)m * 512 + n] = f2h(acc[i][j][r] + bj);
      }
  }
}

// ---------- fusion GEMM: diff = Xdiff @ W^T ; out = tl2 + (tl1-tl2)*sigmoid(diff) ----------
__global__ __launch_bounds__(256) void gemm_fusion(
    const unsigned short* __restrict__ X, const unsigned short* __restrict__ Wf,
    const float* __restrict__ tl1, const float* __restrict__ tl2, float* __restrict__ outp) {
  const int nt = blockIdx.x, mt = blockIdx.y;
  __shared__ __align__(16) unsigned short Xs[128][72];
  __shared__ __align__(16) unsigned short Wt[128][72];
  const int tid = threadIdx.x, lane = tid & 63, w = tid >> 6;
  const int col = lane & 15, grp = lane >> 4;
  const int wm = (w >> 1) * 64, wn = (w & 1) * 64;

  const float4v zero4 = {0.f, 0.f, 0.f, 0.f};
  float4v acc[4][4];
#pragma unroll
  for (int i = 0; i < 4; ++i)
#pragma unroll
    for (int j = 0; j < 4; ++j) acc[i][j] = zero4;

  const int lr = tid >> 3, lc = (tid & 7) * 8;
  for (int k0 = 0; k0 < 512; k0 += 64) {
#pragma unroll
    for (int p = 0; p < 4; ++p) {
      *(half8*)&Xs[lr + 32 * p][lc] =
          *(const half8*)&X[(size_t)(mt * 128 + lr + 32 * p) * 512 + k0 + lc];
      *(half8*)&Wt[lr + 32 * p][lc] =
          *(const half8*)&Wf[(size_t)(nt * 128 + lr + 32 * p) * 512 + k0 + lc];
    }
    __syncthreads();
#pragma unroll
    for (int kk = 0; kk < 64; kk += 32) {
      half8 af[4], bf[4];
#pragma unroll
      for (int i = 0; i < 4; ++i) af[i] = *(const half8*)&Xs[wm + i * 16 + col][kk + grp * 8];
#pragma unroll
      for (int j = 0; j < 4; ++j) bf[j] = *(const half8*)&Wt[wn + j * 16 + col][kk + grp * 8];
#pragma unroll
      for (int i = 0; i < 4; ++i)
#pragma unroll
        for (int j = 0; j < 4; ++j)
          acc[i][j] = mfma16x16x32_f16(af[i], bf[j], acc[i][j]);
    }
    __syncthreads();
  }
#pragma unroll
  for (int j = 0; j < 4; ++j) {
    const int n = nt * 128 + wn + j * 16 + col;
#pragma unroll
    for (int i = 0; i < 4; ++i)
#pragma unroll
      for (int r = 0; r < 4; ++r) {
        const int m = mt * 128 + wm + i * 16 + grp * 4 + r;
        const size_t off = (size_t)m * 512 + n;
        const float t1 = tl1[off], t2 = tl2[off];
        const float sg = 1.0f / (1.0f + __expf(-acc[i][j][r]));
        outp[off] = t2 + (t1 - t2) * sg;
      }
  }
}

// ---------- attention, single-S-pass, 512 threads per (b,h[,chunk]) ----------
// S[t,s] = sum_dd K[dd,t]*V[dd,s] (×temp); per 2 t-tiles: Z via one barrier;
// P' = exp(S)/Z in fp16 (<=1), Q fed unscaled as fp16 -> out = Q @ P'.
template <int T>
__global__ __launch_bounds__(512) void attn_kernel(
    const unsigned short* __restrict__ Qb, const unsigned short* __restrict__ Kb,
    const unsigned short* __restrict__ Vb, const float* __restrict__ temp_base,
    const float* add_src,  // no restrict: may alias outp (in-place tl2)
    float* outp, int chunk_elems,
    const float* __restrict__ tl1_src, unsigned short* __restrict__ diff_out) {
  constexpr int NT = T / 16;         // t-tiles
  constexpr int NSW = (T / 16) / 8;  // s-tiles per wave (8 waves split s)
  constexpr int SLAB = T * 32;
  const int h = blockIdx.x, b = blockIdx.y, cb = blockIdx.z;
  const int base = b * (384 * 512) + cb * chunk_elems + h * SLAB;
  const float tscale = temp_base[cb * 16 + h];

  __shared__ __align__(16) unsigned short KVt[T][40];  // V then K, transposed [t][dd]
  __shared__ __align__(16) float Zp[2][2][8][16];      // [parity][tile-in-pair][wave][t]

  const int tid = threadIdx.x, lane = tid & 63, w = tid >> 6;
  const int col = lane & 15, grp = lane >> 4;

  // --- staging: column-gather transpose, conflict-free b128 LDS writes ---
  // thread f: t = f>>2, blk = (f&3)*8; gathers 8 dd values (u16, stride T) and
  // writes one contiguous 16B chunk. Global side: 32 lanes share each 64B line.
  auto stage = [&](const unsigned short* src) {
    constexpr int ITER = (T * 4) / 512;
#pragma unroll
    for (int p = 0; p < ITER; ++p) {
      const int f = p * 512 + tid;
      const int t = f >> 2, blk = (f & 3) * 8;
      unsigned short tmp[8];
#pragma unroll
      for (int i = 0; i < 8; ++i) tmp[i] = src[(size_t)(blk + i) * T + t];
      *(uint4*)&KVt[t][blk] = *(const uint4*)tmp;
    }
  };

  stage(Vb + base);
  __syncthreads();
  half8 vfr[NSW];  // this wave's V fragments (s-strips w + si*8)
#pragma unroll
  for (int si = 0; si < NSW; ++si)
    vfr[si] = *(const half8*)&KVt[(w + si * 8) * 16 + col][grp * 8];
  __syncthreads();
  stage(Kb + base);  // reuse buffer for K
  __syncthreads();

  const float4v zero4 = {0.f, 0.f, 0.f, 0.f};
  const unsigned short* Qsl = Qb + base;
  float4v oacc[NSW][2];
#pragma unroll
  for (int si = 0; si < NSW; ++si) {
    oacc[si][0] = zero4;
    oacc[si][1] = zero4;
  }

  for (int kk = 0; kk < NT / 2; ++kk) {
    const int par = kk & 1;
    float pe[2][NSW][4];
    // --- S + exp + in-wave Z partial for both tiles of the pair ---
#pragma unroll
    for (int u = 0; u < 2; ++u) {
      const int tt = kk * 2 + u;
      half8 kf = *(const half8*)&KVt[tt * 16 + col][grp * 8];
      float z0 = 0.f, z1 = 0.f, z2 = 0.f, z3 = 0.f;
#pragma unroll
      for (int si = 0; si < NSW; ++si) {
        float4v s = mfma16x16x32_f16(kf, vfr[si], zero4);
        pe[u][si][0] = __expf(s[0] * tscale);
        pe[u][si][1] = __expf(s[1] * tscale);
        pe[u][si][2] = __expf(s[2] * tscale);
        pe[u][si][3] = __expf(s[3] * tscale);
        z0 += pe[u][si][0];
        z1 += pe[u][si][1];
        z2 += pe[u][si][2];
        z3 += pe[u][si][3];
      }
#pragma unroll
      for (int m = 1; m < 16; m <<= 1) {
        z0 += __shfl_xor(z0, m);
        z1 += __shfl_xor(z1, m);
        z2 += __shfl_xor(z2, m);
        z3 += __shfl_xor(z3, m);
      }
      if (col == 0) {
        float4v zv = {z0, z1, z2, z3};
        *(float4v*)&Zp[par][u][w][grp * 4] = zv;
      }
    }
    // Q fragments for both tiles (issue before barrier to hide latency)
    half4v qa[2][2];
#pragma unroll
    for (int u = 0; u < 2; ++u) {
      const int toff = (kk * 2 + u) * 16 + grp * 4;
      qa[u][0] = *(const half4v*)(Qsl + col * T + toff);
      qa[u][1] = *(const half4v*)(Qsl + (16 + col) * T + toff);
    }
    __syncthreads();
    // --- combine 8 wave partials, then PV ---
#pragma unroll
    for (int u = 0; u < 2; ++u) {
      float4v zs = zero4;
#pragma unroll
      for (int ww = 0; ww < 8; ++ww) zs += *(const float4v*)&Zp[par][u][ww][grp * 4];
      const float zi0 = 1.0f / zs[0], zi1 = 1.0f / zs[1], zi2 = 1.0f / zs[2],
                  zi3 = 1.0f / zs[3];
#pragma unroll
      for (int si = 0; si < NSW; ++si) {
        half4v pb;
        pb[0] = (_Float16)(pe[u][si][0] * zi0);
        pb[1] = (_Float16)(pe[u][si][1] * zi1);
        pb[2] = (_Float16)(pe[u][si][2] * zi2);
        pb[3] = (_Float16)(pe[u][si][3] * zi3);
        oacc[si][0] = mfma16x16x16_f16(qa[u][0], pb, oacc[si][0]);
        oacc[si][1] = mfma16x16x16_f16(qa[u][1], pb, oacc[si][1]);
      }
    }
  }

  // --- epilogue ---
#pragma unroll
  for (int si = 0; si < NSW; ++si) {
    const int s = (w + si * 8) * 16 + col;
#pragma unroll
    for (int m0 = 0; m0 < 2; ++m0) {
#pragma unroll
      for (int r = 0; r < 4; ++r) {
        const int dd = m0 * 16 + grp * 4 + r;
        const int off = base + dd * T + s;
        float v = oacc[si][m0][r];
        if (add_src) v += add_src[off];
        outp[off] = v;
        if (diff_out) diff_out[off] = f2h(tl1_src[off] - v);
      }
    }
  }
}

// ---------- layernorm over rows of 512 -> fp16 ----------
__global__ __launch_bounds__(256) void ln_kernel(const float* __restrict__ xin,
                                                 const float* __restrict__ g,
                                                 const float* __restrict__ bb,
                                                 unsigned short* __restrict__ y) {
  const int row = blockIdx.x * 4 + (threadIdx.x >> 6);
  const int lane = threadIdx.x & 63;
  const float* xr = xin + (size_t)row * 512;
  float4 v0 = *(const float4*)&xr[lane * 8];
  float4 v1 = *(const float4*)&xr[lane * 8 + 4];
  float s = v0.x + v0.y + v0.z + v0.w + v1.x + v1.y + v1.z + v1.w;
  float q = v0.x * v0.x + v0.y * v0.y + v0.z * v0.z + v0.w * v0.w +
            v1.x * v1.x + v1.y * v1.y + v1.z * v1.z + v1.w * v1.w;
#pragma unroll
  for (int m = 1; m < 64; m <<= 1) {
    s += __shfl_xor(s, m);
    q += __shfl_xor(q, m);
  }
  const float mean = s * (1.0f / 512.0f);
  const float var = q * (1.0f / 512.0f) - mean * mean;
  const float rs = rsqrtf(var + 1e-5f);
  float4 g0 = *(const float4*)&g[lane * 8];
  float4 g1 = *(const float4*)&g[lane * 8 + 4];
  float4 b0 = *(const float4*)&bb[lane * 8];
  float4 b1 = *(const float4*)&bb[lane * 8 + 4];
  uint4 o;
  o.x = (unsigned)f2h((v0.x - mean) * rs * g0.x + b0.x) |
        ((unsigned)f2h((v0.y - mean) * rs * g0.y + b0.y) << 16);
  o.y = (unsigned)f2h((v0.z - mean) * rs * g0.z + b0.z) |
        ((unsigned)f2h((v0.w - mean) * rs * g0.w + b0.w) << 16);
  o.z = (unsigned)f2h((v1.x - mean) * rs * g1.x + b1.x) |
        ((unsigned)f2h((v1.y - mean) * rs * g1.y + b1.y) << 16);
  o.w = (unsigned)f2h((v1.z - mean) * rs * g1.z + b1.z) |
        ((unsigned)f2h((v1.w - mean) * rs * g1.w + b1.w) << 16);
  *(uint4*)&y[(size_t)row * 512 + lane * 8] = o;
}

// ---------- launch ----------
extern "C" void kernel_launch(void* const* d_in, const int* in_sizes, int n_in,
                              void* d_out, int out_size, void* d_ws, size_t ws_size,
                              hipStream_t stream) {
  const float* x = (const float*)d_in[0];
  const float* qw = (const float*)d_in[1];
  const float* qb = (const float*)d_in[2];
  const float* kw = (const float*)d_in[3];
  const float* kb = (const float*)d_in[4];
  const float* vw = (const float*)d_in[5];
  const float* vb = (const float*)d_in[6];
  const float* temp = (const float*)d_in[7];
  const float* ln_g = (const float*)d_in[8];
  const float* ln_b = (const float*)d_in[9];
  const float* fus_w = (const float*)d_in[10];
  // fus_b (d_in[11]) cancels in the 2-way softmax; num_heads (d_in[12]) fixed at 16
  float* out = (float*)d_out;

  const size_t NE = (size_t)32 * 384 * 512;  // 6291456
  const size_t WE = (size_t)5 * 512 * 512;   // 1310720

  char* p = (char*)d_ws;
  auto alloc = [&](size_t bytes) {
    char* r = p;
    p += (bytes + 255) & ~(size_t)255;
    return r;
  };
  unsigned short* xb = (unsigned short*)alloc(NE * 2);
  unsigned short* wqb = (unsigned short*)alloc(WE * 2);
  unsigned short* wkb = (unsigned short*)alloc(WE * 2);
  unsigned short* wvb = (unsigned short*)alloc(WE * 2);
  unsigned short* fwb = (unsigned short*)alloc((size_t)512 * 512 * 2);
  unsigned short* Qb = (unsigned short*)alloc(NE * 2);
  unsigned short* Kb = (unsigned short*)alloc(NE * 2);
  unsigned short* Vb = (unsigned short*)alloc(NE * 2);
  float* xres = (float*)alloc(NE * 4);  // x_ , later tl2 (in place)
  float* tl1 = (float*)alloc(NE * 4);
  unsigned short* yb = (unsigned short*)alloc(NE * 2);  // LN output, later diff (fp16)

  // converts
  cvt_f32_f16<<<(int)((NE / 4 + 255) / 256), 256, 0, stream>>>(x, xb, (int)(NE / 4));
  cvt_f32_f16<<<(int)((WE / 4 + 255) / 256), 256, 0, stream>>>(qw, wqb, (int)(WE / 4));
  cvt_f32_f16<<<(int)((WE / 4 + 255) / 256), 256, 0, stream>>>(kw, wkb, (int)(WE / 4));
  cvt_f32_f16<<<(int)((WE / 4 + 255) / 256), 256, 0, stream>>>(vw, wvb, (int)(WE / 4));
  cvt_f32_f16<<<256, 256, 0, stream>>>(fus_w, fwb, 512 * 512 / 4);

  // block 0 projections + attention -> x_ (xres)
  gemm_qkv<<<dim3(4, 96, 3), 256, 0, stream>>>(xb, wqb, wkb, wvb, qb, kb, vb, Qb, Kb, Vb, 0, 0);
  attn_kernel<384><<<dim3(16, 32, 1), 512, 0, stream>>>(Qb, Kb, Vb, temp, nullptr, xres, 0,
                                                        nullptr, nullptr);
  // blocks 1-3 (chunked) projections + attention -> tl1 = concat + x_
  gemm_qkv<<<dim3(4, 96, 3), 256, 0, stream>>>(xb, wqb, wkb, wvb, qb, kb, vb, Qb, Kb, Vb, 1, 0);
  attn_kernel<128><<<dim3(16, 32, 3), 512, 0, stream>>>(Qb, Kb, Vb, temp + 16, xres, tl1,
                                                        128 * 512, nullptr, nullptr);
  // layernorm -> y (fp16)
  ln_kernel<<<12288 / 4, 256, 0, stream>>>(tl1, ln_g, ln_b, yb);
  // block 4 projections + attention -> tl2 = out + x_ (in-place into xres), diff -> yb
  gemm_qkv<<<dim3(4, 96, 3), 256, 0, stream>>>(yb, wqb, wkb, wvb, qb, kb, vb, Qb, Kb, Vb, 0, 4);
  attn_kernel<384><<<dim3(16, 32, 1), 512, 0, stream>>>(Qb, Kb, Vb, temp + 64, xres, xres, 0,
                                                        tl1, yb);
  // fusion: out = tl2 + (tl1-tl2)*sigmoid((tl1-tl2)@fus_w^T)
  gemm_fusion<<<dim3(4, 96, 1), 256, 0, stream>>>(yb, fwb, tl1, xres, out);

  (void)in_sizes; (void)n_in; (void)out_size; (void)ws_size;
}

// Round 6
// 413.626 us; speedup vs baseline: 1.1297x; 1.0117x over previous
//
#include <hip/hip_runtime.h>

// ---------- types ----------
typedef __attribute__((ext_vector_type(8))) _Float16 half8;
typedef __attribute__((ext_vector_type(4))) _Float16 half4v;
typedef __attribute__((ext_vector_type(4))) float float4v;

// MFMA wrappers. Host pass chokes on top-level __has_builtin dispatch
// (round-1 failure), so guard with __HIP_DEVICE_COMPILE__.
__device__ __forceinline__ float4v mfma16x16x32_f16(half8 a, half8 b, float4v c) {
#if defined(__HIP_DEVICE_COMPILE__)
#if __has_builtin(__builtin_amdgcn_mfma_f32_16x16x32_f16)
  return __builtin_amdgcn_mfma_f32_16x16x32_f16(a, b, c, 0, 0, 0);
#elif __has_builtin(__builtin_amdgcn_mfma_f32_16x16x32f16)
  return __builtin_amdgcn_mfma_f32_16x16x32f16(a, b, c, 0, 0, 0);
#else
#error "no 16x16x32 f16 mfma"
#endif
#else
  (void)a; (void)b;
  return c;
#endif
}

__device__ __forceinline__ float4v mfma16x16x16_f16(half4v a, half4v b, float4v c) {
#if defined(__HIP_DEVICE_COMPILE__)
#if __has_builtin(__builtin_amdgcn_mfma_f32_16x16x16f16)
  return __builtin_amdgcn_mfma_f32_16x16x16f16(a, b, c, 0, 0, 0);
#elif __has_builtin(__builtin_amdgcn_mfma_f32_16x16x16_f16)
  return __builtin_amdgcn_mfma_f32_16x16x16_f16(a, b, c, 0, 0, 0);
#else
#error "no 16x16x16 f16 mfma"
#endif
#else
  (void)a; (void)b;
  return c;
#endif
}

// async global->LDS, 16B per lane. LDS dest must be wave-uniform base + lane*16
// (our staging slots are lane-contiguous by construction).
__device__ __forceinline__ void gl_lds16(const unsigned short* g, unsigned short* l) {
#if defined(__HIP_DEVICE_COMPILE__)
#if __has_builtin(__builtin_amdgcn_global_load_lds)
  __builtin_amdgcn_global_load_lds(
      (const __attribute__((address_space(1))) unsigned int*)g,
      (__attribute__((address_space(3))) unsigned int*)l, 16, 0, 0);
#else
  *(uint4*)l = *(const uint4*)g;  // fallback: VGPR round-trip
#endif
#else
  (void)g; (void)l;
#endif
}

// exp2 (v_exp_f32) if available; fallback is numerically identical via __expf.
__device__ __forceinline__ float fexp2(float x) {
#if defined(__HIP_DEVICE_COMPILE__)
#if __has_builtin(__builtin_amdgcn_exp2f)
  return __builtin_amdgcn_exp2f(x);
#else
  return __expf(x * 0.6931471805599453f);
#endif
#else
  return x;
#endif
}

__device__ __forceinline__ unsigned short f2h(float f) {
  union { _Float16 h; unsigned short u; } v;
  v.h = (_Float16)f;
  return v.u;
}

// ---------- fp32 -> fp16 convert ----------
__global__ __launch_bounds__(256) void cvt_f32_f16(const float* __restrict__ in,
                                                   unsigned short* __restrict__ out, int n4) {
  int i = blockIdx.x * 256 + threadIdx.x;
  if (i >= n4) return;
  float4 v = ((const float4*)in)[i];
  uint2 o;
  o.x = (unsigned)f2h(v.x) | ((unsigned)f2h(v.y) << 16);
  o.y = (unsigned)f2h(v.z) | ((unsigned)f2h(v.w) << 16);
  ((uint2*)out)[i] = o;
}

// ---------- shared GEMM core: 128x128 tile, K=512, global_load_lds staging ----------
// LDS layout: unpadded [128][64] shorts with XOR chunk swizzle:
//   LDS slot (row r, 16B-chunk sc) holds global chunk sc^(r&7);
//   reader of chunk c uses slot c^(r&7). Staging slots are lane-contiguous
//   (slot = rnd*256 + tid), satisfying global_load_lds's dest constraint.
#define GEMM_K_LOOP(XPTR, WPTR)                                                        \
  const int sw = col & 7;                                                              \
  for (int k0 = 0; k0 < 512; k0 += 64) {                                               \
    const unsigned short* Xg = (XPTR) + k0;                                            \
    const unsigned short* Wg = (WPTR) + k0;                                            \
    _Pragma("unroll") for (int rnd = 0; rnd < 4; ++rnd) {                              \
      const int slot = rnd * 256 + tid;                                                \
      const int r = slot >> 3;                                                         \
      const int c = (slot & 7) ^ (r & 7);                                              \
      gl_lds16(Xg + (size_t)r * 512 + c * 8, &Xs[slot * 8]);                           \
      gl_lds16(Wg + (size_t)r * 512 + c * 8, &Wt[slot * 8]);                           \
    }                                                                                  \
    __syncthreads();                                                                   \
    _Pragma("unroll") for (int kk = 0; kk < 2; ++kk) {                                 \
      half8 af[4], bf[4];                                                              \
      _Pragma("unroll") for (int i = 0; i < 4; ++i) {                                  \
        const int r = wm + i * 16 + col;                                               \
        af[i] = *(const half8*)&Xs[r * 64 + ((kk * 4 + grp) ^ sw) * 8];                \
      }                                                                                \
      _Pragma("unroll") for (int j = 0; j < 4; ++j) {                                  \
        const int r = wn + j * 16 + col;                                               \
        bf[j] = *(const half8*)&Wt[r * 64 + ((kk * 4 + grp) ^ sw) * 8];                \
      }                                                                                \
      _Pragma("unroll") for (int i = 0; i < 4; ++i)                                    \
          _Pragma("unroll") for (int j = 0; j < 4; ++j)                                \
              acc[i][j] = mfma16x16x32_f16(af[i], bf[j], acc[i][j]);                   \
    }                                                                                  \
    __syncthreads();                                                                   \
  }

// ---------- QKV projection GEMM: C = X @ W[widx]^T + b[widx], fp16 in/out ----------
__global__ __launch_bounds__(256) void gemm_qkv(
    const unsigned short* __restrict__ X,
    const unsigned short* __restrict__ Wq, const unsigned short* __restrict__ Wk,
    const unsigned short* __restrict__ Wv,
    const float* __restrict__ bq, const float* __restrict__ bk, const float* __restrict__ bv,
    unsigned short* __restrict__ Cq, unsigned short* __restrict__ Ck, unsigned short* __restrict__ Cv,
    int wsel_mode, int widx_fixed) {
  const int nt = blockIdx.x, mt = blockIdx.y, z = blockIdx.z;
  const unsigned short* W = (z == 0) ? Wq : ((z == 1) ? Wk : Wv);
  const float* bias = (z == 0) ? bq : ((z == 1) ? bk : bv);
  unsigned short* C = (z == 0) ? Cq : ((z == 1) ? Ck : Cv);
  const int widx = wsel_mode ? (1 + (mt % 3)) : widx_fixed;
  W += (size_t)widx * 512 * 512;
  bias += widx * 512;

  __shared__ __align__(16) unsigned short Xs[128 * 64];
  __shared__ __align__(16) unsigned short Wt[128 * 64];
  const int tid = threadIdx.x, lane = tid & 63, w = tid >> 6;
  const int col = lane & 15, grp = lane >> 4;
  const int wm = (w >> 1) * 64, wn = (w & 1) * 64;

  const float4v zero4 = {0.f, 0.f, 0.f, 0.f};
  float4v acc[4][4];
#pragma unroll
  for (int i = 0; i < 4; ++i)
#pragma unroll
    for (int j = 0; j < 4; ++j) acc[i][j] = zero4;

  GEMM_K_LOOP(X + (size_t)mt * 128 * 512, W + (size_t)nt * 128 * 512)

#pragma unroll
  for (int j = 0; j < 4; ++j) {
    const int n = nt * 128 + wn + j * 16 + col;
    const float bj = bias[n];
#pragma unroll
    for (int i = 0; i < 4; ++i)
#pragma unroll
      for (int r = 0; r < 4; ++r) {
        const int m = mt * 128 + wm + i * 16 + grp * 4 + r;
        C[(size_t)m * 512 + n] = f2h(acc[i][j][r] + bj);
      }
  }
}

// ---------- fusion GEMM: diff = Xdiff @ W^T ; out = tl2 + (tl1-tl2)*sigmoid(diff) ----------
__global__ __launch_bounds__(256) void gemm_fusion(
    const unsigned short* __restrict__ X, const unsigned short* __restrict__ Wf,
    const float* __restrict__ tl1, const float* __restrict__ tl2, float* __restrict__ outp) {
  const int nt = blockIdx.x, mt = blockIdx.y;
  __shared__ __align__(16) unsigned short Xs[128 * 64];
  __shared__ __align__(16) unsigned short Wt[128 * 64];
  const int tid = threadIdx.x, lane = tid & 63, w = tid >> 6;
  const int col = lane & 15, grp = lane >> 4;
  const int wm = (w >> 1) * 64, wn = (w & 1) * 64;

  const float4v zero4 = {0.f, 0.f, 0.f, 0.f};
  float4v acc[4][4];
#pragma unroll
  for (int i = 0; i < 4; ++i)
#pragma unroll
    for (int j = 0; j < 4; ++j) acc[i][j] = zero4;

  GEMM_K_LOOP(X + (size_t)mt * 128 * 512, Wf + (size_t)nt * 128 * 512)

#pragma unroll
  for (int j = 0; j < 4; ++j) {
    const int n = nt * 128 + wn + j * 16 + col;
#pragma unroll
    for (int i = 0; i < 4; ++i)
#pragma unroll
      for (int r = 0; r < 4; ++r) {
        const int m = mt * 128 + wm + i * 16 + grp * 4 + r;
        const size_t off = (size_t)m * 512 + n;
        const float t1 = tl1[off], t2 = tl2[off];
        const float sg = 1.0f / (1.0f + __expf(-acc[i][j][r]));
        outp[off] = t2 + (t1 - t2) * sg;
      }
  }
}

// ---------- attention, single-S-pass, 512 threads per (b,h[,chunk]) ----------
// S[t,s] = sum_dd K[dd,t]*V[dd,s] (×temp); per 2 t-tiles: Z via one barrier;
// P' = exp(S)/Z in fp16 (<=1), Q fed unscaled as fp16 -> out = Q @ P'.
template <int T>
__global__ __launch_bounds__(512) void attn_kernel(
    const unsigned short* __restrict__ Qb, const unsigned short* __restrict__ Kb,
    const unsigned short* __restrict__ Vb, const float* __restrict__ temp_base,
    const float* add_src,  // no restrict: may alias outp (in-place tl2)
    float* outp, int chunk_elems,
    const float* __restrict__ tl1_src, unsigned short* __restrict__ diff_out) {
  constexpr int NT = T / 16;         // t-tiles
  constexpr int NSW = (T / 16) / 8;  // s-tiles per wave (8 waves split s)
  constexpr int SLAB = T * 32;
  const int h = blockIdx.x, b = blockIdx.y, cb = blockIdx.z;
  const int base = b * (384 * 512) + cb * chunk_elems + h * SLAB;
  const float tl2e = temp_base[cb * 16 + h] * 1.4426950408889634f;  // temp*log2(e)

  __shared__ __align__(16) unsigned short KVt[T][40];  // V then K, transposed [t][dd]
  __shared__ __align__(16) float Zp[2][2][8][16];      // [parity][tile-in-pair][wave][t]

  const int tid = threadIdx.x, lane = tid & 63, w = tid >> 6;
  const int col = lane & 15, grp = lane >> 4;

  // --- staging: column-gather transpose, conflict-free b128 LDS writes ---
  auto stage = [&](const unsigned short* src) {
    constexpr int ITER = (T * 4) / 512;
#pragma unroll
    for (int p = 0; p < ITER; ++p) {
      const int f = p * 512 + tid;
      const int t = f >> 2, blk = (f & 3) * 8;
      unsigned short tmp[8];
#pragma unroll
      for (int i = 0; i < 8; ++i) tmp[i] = src[(size_t)(blk + i) * T + t];
      *(uint4*)&KVt[t][blk] = *(const uint4*)tmp;
    }
  };

  stage(Vb + base);
  __syncthreads();
  half8 vfr[NSW];  // this wave's V fragments (s-strips w + si*8)
#pragma unroll
  for (int si = 0; si < NSW; ++si)
    vfr[si] = *(const half8*)&KVt[(w + si * 8) * 16 + col][grp * 8];
  __syncthreads();
  stage(Kb + base);  // reuse buffer for K
  __syncthreads();

  const float4v zero4 = {0.f, 0.f, 0.f, 0.f};
  const unsigned short* Qsl = Qb + base;
  float4v oacc[NSW][2];
#pragma unroll
  for (int si = 0; si < NSW; ++si) {
    oacc[si][0] = zero4;
    oacc[si][1] = zero4;
  }

  for (int kk = 0; kk < NT / 2; ++kk) {
    const int par = kk & 1;
    float pe[2][NSW][4];
    // --- S + exp + in-wave Z partial for both tiles of the pair ---
#pragma unroll
    for (int u = 0; u < 2; ++u) {
      const int tt = kk * 2 + u;
      half8 kf = *(const half8*)&KVt[tt * 16 + col][grp * 8];
      float z0 = 0.f, z1 = 0.f, z2 = 0.f, z3 = 0.f;
#pragma unroll
      for (int si = 0; si < NSW; ++si) {
        float4v s = mfma16x16x32_f16(kf, vfr[si], zero4);
        pe[u][si][0] = fexp2(s[0] * tl2e);
        pe[u][si][1] = fexp2(s[1] * tl2e);
        pe[u][si][2] = fexp2(s[2] * tl2e);
        pe[u][si][3] = fexp2(s[3] * tl2e);
        z0 += pe[u][si][0];
        z1 += pe[u][si][1];
        z2 += pe[u][si][2];
        z3 += pe[u][si][3];
      }
#pragma unroll
      for (int m = 1; m < 16; m <<= 1) {
        z0 += __shfl_xor(z0, m);
        z1 += __shfl_xor(z1, m);
        z2 += __shfl_xor(z2, m);
        z3 += __shfl_xor(z3, m);
      }
      if (col == 0) {
        float4v zv = {z0, z1, z2, z3};
        *(float4v*)&Zp[par][u][w][grp * 4] = zv;
      }
    }
    // Q fragments for both tiles (issue before barrier to hide latency)
    half4v qa[2][2];
#pragma unroll
    for (int u = 0; u < 2; ++u) {
      const int toff = (kk * 2 + u) * 16 + grp * 4;
      qa[u][0] = *(const half4v*)(Qsl + col * T + toff);
      qa[u][1] = *(const half4v*)(Qsl + (16 + col) * T + toff);
    }
    __syncthreads();
    // --- combine 8 wave partials, then PV ---
#pragma unroll
    for (int u = 0; u < 2; ++u) {
      float4v zs = zero4;
#pragma unroll
      for (int ww = 0; ww < 8; ++ww) zs += *(const float4v*)&Zp[par][u][ww][grp * 4];
      const float zi0 = 1.0f / zs[0], zi1 = 1.0f / zs[1], zi2 = 1.0f / zs[2],
                  zi3 = 1.0f / zs[3];
#pragma unroll
      for (int si = 0; si < NSW; ++si) {
        half4v pb;
        pb[0] = (_Float16)(pe[u][si][0] * zi0);
        pb[1] = (_Float16)(pe[u][si][1] * zi1);
        pb[2] = (_Float16)(pe[u][si][2] * zi2);
        pb[3] = (_Float16)(pe[u][si][3] * zi3);
        oacc[si][0] = mfma16x16x16_f16(qa[u][0], pb, oacc[si][0]);
        oacc[si][1] = mfma16x16x16_f16(qa[u][1], pb, oacc[si][1]);
      }
    }
  }

  // --- epilogue ---
#pragma unroll
  for (int si = 0; si < NSW; ++si) {
    const int s = (w + si * 8) * 16 + col;
#pragma unroll
    for (int m0 = 0; m0 < 2; ++m0) {
#pragma unroll
      for (int r = 0; r < 4; ++r) {
        const int dd = m0 * 16 + grp * 4 + r;
        const int off = base + dd * T + s;
        float v = oacc[si][m0][r];
        if (add_src) v += add_src[off];
        outp[off] = v;
        if (diff_out) diff_out[off] = f2h(tl1_src[off] - v);
      }
    }
  }
}

// ---------- layernorm over rows of 512 -> fp16 ----------
__global__ __launch_bounds__(256) void ln_kernel(const float* __restrict__ xin,
                                                 const float* __restrict__ g,
                                                 const float* __restrict__ bb,
                                                 unsigned short* __restrict__ y) {
  const int row = blockIdx.x * 4 + (threadIdx.x >> 6);
  const int lane = threadIdx.x & 63;
  const float* xr = xin + (size_t)row * 512;
  float4 v0 = *(const float4*)&xr[lane * 8];
  float4 v1 = *(const float4*)&xr[lane * 8 + 4];
  float s = v0.x + v0.y + v0.z + v0.w + v1.x + v1.y + v1.z + v1.w;
  float q = v0.x * v0.x + v0.y * v0.y + v0.z * v0.z + v0.w * v0.w +
            v1.x * v1.x + v1.y * v1.y + v1.z * v1.z + v1.w * v1.w;
#pragma unroll
  for (int m = 1; m < 64; m <<= 1) {
    s += __shfl_xor(s, m);
    q += __shfl_xor(q, m);
  }
  const float mean = s * (1.0f / 512.0f);
  const float var = q * (1.0f / 512.0f) - mean * mean;
  const float rs = rsqrtf(var + 1e-5f);
  float4 g0 = *(const float4*)&g[lane * 8];
  float4 g1 = *(const float4*)&g[lane * 8 + 4];
  float4 b0 = *(const float4*)&bb[lane * 8];
  float4 b1 = *(const float4*)&bb[lane * 8 + 4];
  uint4 o;
  o.x = (unsigned)f2h((v0.x - mean) * rs * g0.x + b0.x) |
        ((unsigned)f2h((v0.y - mean) * rs * g0.y + b0.y) << 16);
  o.y = (unsigned)f2h((v0.z - mean) * rs * g0.z + b0.z) |
        ((unsigned)f2h((v0.w - mean) * rs * g0.w + b0.w) << 16);
  o.z = (unsigned)f2h((v1.x - mean) * rs * g1.x + b1.x) |
        ((unsigned)f2h((v1.y - mean) * rs * g1.y + b1.y) << 16);
  o.w = (unsigned)f2h((v1.z - mean) * rs * g1.z + b1.z) |
        ((unsigned)f2h((v1.w - mean) * rs * g1.w + b1.w) << 16);
  *(uint4*)&y[(size_t)row * 512 + lane * 8] = o;
}

// ---------- launch ----------
extern "C" void kernel_launch(void* const* d_in, const int* in_sizes, int n_in,
                              void* d_out, int out_size, void* d_ws, size_t ws_size,
                              hipStream_t stream) {
  const float* x = (const float*)d_in[0];
  const float* qw = (const float*)d_in[1];
  const float* qb = (const float*)d_in[2];
  const float* kw = (const float*)d_in[3];
  const float* kb = (const float*)d_in[4];
  const float* vw = (const float*)d_in[5];
  const float* vb = (const float*)d_in[6];
  const float* temp = (const float*)d_in[7];
  const float* ln_g = (const float*)d_in[8];
  const float* ln_b = (const float*)d_in[9];
  const float* fus_w = (const float*)d_in[10];
  // fus_b (d_in[11]) cancels in the 2-way softmax; num_heads (d_in[12]) fixed at 16
  float* out = (float*)d_out;

  const size_t NE = (size_t)32 * 384 * 512;  // 6291456
  const size_t WE = (size_t)5 * 512 * 512;   // 1310720

  char* p = (char*)d_ws;
  auto alloc = [&](size_t bytes) {
    char* r = p;
    p += (bytes + 255) & ~(size_t)255;
    return r;
  };
  unsigned short* xb = (unsigned short*)alloc(NE * 2);
  unsigned short* wqb = (unsigned short*)alloc(WE * 2);
  unsigned short* wkb = (unsigned short*)alloc(WE * 2);
  unsigned short* wvb = (unsigned short*)alloc(WE * 2);
  unsigned short* fwb = (unsigned short*)alloc((size_t)512 * 512 * 2);
  unsigned short* Qb = (unsigned short*)alloc(NE * 2);
  unsigned short* Kb = (unsigned short*)alloc(NE * 2);
  unsigned short* Vb = (unsigned short*)alloc(NE * 2);
  float* xres = (float*)alloc(NE * 4);  // x_ , later tl2 (in place)
  float* tl1 = (float*)alloc(NE * 4);
  unsigned short* yb = (unsigned short*)alloc(NE * 2);  // LN output, later diff (fp16)

  // converts
  cvt_f32_f16<<<(int)((NE / 4 + 255) / 256), 256, 0, stream>>>(x, xb, (int)(NE / 4));
  cvt_f32_f16<<<(int)((WE / 4 + 255) / 256), 256, 0, stream>>>(qw, wqb, (int)(WE / 4));
  cvt_f32_f16<<<(int)((WE / 4 + 255) / 256), 256, 0, stream>>>(kw, wkb, (int)(WE / 4));
  cvt_f32_f16<<<(int)((WE / 4 + 255) / 256), 256, 0, stream>>>(vw, wvb, (int)(WE / 4));
  cvt_f32_f16<<<256, 256, 0, stream>>>(fus_w, fwb, 512 * 512 / 4);

  // block 0 projections + attention -> x_ (xres)
  gemm_qkv<<<dim3(4, 96, 3), 256, 0, stream>>>(xb, wqb, wkb, wvb, qb, kb, vb, Qb, Kb, Vb, 0, 0);
  attn_kernel<384><<<dim3(16, 32, 1), 512, 0, stream>>>(Qb, Kb, Vb, temp, nullptr, xres, 0,
                                                        nullptr, nullptr);
  // blocks 1-3 (chunked) projections + attention -> tl1 = concat + x_
  gemm_qkv<<<dim3(4, 96, 3), 256, 0, stream>>>(xb, wqb, wkb, wvb, qb, kb, vb, Qb, Kb, Vb, 1, 0);
  attn_kernel<128><<<dim3(16, 32, 3), 512, 0, stream>>>(Qb, Kb, Vb, temp + 16, xres, tl1,
                                                        128 * 512, nullptr, nullptr);
  // layernorm -> y (fp16)
  ln_kernel<<<12288 / 4, 256, 0, stream>>>(tl1, ln_g, ln_b, yb);
  // block 4 projections + attention -> tl2 = out + x_ (in-place into xres), diff -> yb
  gemm_qkv<<<dim3(4, 96, 3), 256, 0, stream>>>(yb, wqb, wkb, wvb, qb, kb, vb, Qb, Kb, Vb, 0, 4);
  attn_kernel<384><<<dim3(16, 32, 1), 512, 0, stream>>>(Qb, Kb, Vb, temp + 64, xres, xres, 0,
                                                        tl1, yb);
  // fusion: out = tl2 + (tl1-tl2)*sigmoid((tl1-tl2)@fus_w^T)
  gemm_fusion<<<dim3(4, 96, 1), 256, 0, stream>>>(yb, fwb, tl1, xres, out);

  (void)in_sizes; (void)n_in; (void)out_size; (void)ws_size;
}

// Round 8
// 404.822 us; speedup vs baseline: 1.1542x; 1.0217x over previous
//
#include <hip/hip_runtime.h>

// ---------- types ----------
typedef __attribute__((ext_vector_type(8))) _Float16 half8;
typedef __attribute__((ext_vector_type(4))) _Float16 half4v;
typedef __attribute__((ext_vector_type(2))) _Float16 half2v;
typedef __attribute__((ext_vector_type(4))) float float4v;

// MFMA wrappers. Host pass chokes on top-level __has_builtin dispatch
// (round-1 failure), so guard with __HIP_DEVICE_COMPILE__.
__device__ __forceinline__ float4v mfma16x16x32_f16(half8 a, half8 b, float4v c) {
#if defined(__HIP_DEVICE_COMPILE__)
#if __has_builtin(__builtin_amdgcn_mfma_f32_16x16x32_f16)
  return __builtin_amdgcn_mfma_f32_16x16x32_f16(a, b, c, 0, 0, 0);
#elif __has_builtin(__builtin_amdgcn_mfma_f32_16x16x32f16)
  return __builtin_amdgcn_mfma_f32_16x16x32f16(a, b, c, 0, 0, 0);
#else
#error "no 16x16x32 f16 mfma"
#endif
#else
  (void)a; (void)b;
  return c;
#endif
}

__device__ __forceinline__ float4v mfma16x16x16_f16(half4v a, half4v b, float4v c) {
#if defined(__HIP_DEVICE_COMPILE__)
#if __has_builtin(__builtin_amdgcn_mfma_f32_16x16x16f16)
  return __builtin_amdgcn_mfma_f32_16x16x16f16(a, b, c, 0, 0, 0);
#elif __has_builtin(__builtin_amdgcn_mfma_f32_16x16x16_f16)
  return __builtin_amdgcn_mfma_f32_16x16x16_f16(a, b, c, 0, 0, 0);
#else
#error "no 16x16x16 f16 mfma"
#endif
#else
  (void)a; (void)b;
  return c;
#endif
}

// async global->LDS, 16B per lane. LDS dest must be wave-uniform base + lane*16.
__device__ __forceinline__ void gl_lds16(const unsigned short* g, unsigned short* l) {
#if defined(__HIP_DEVICE_COMPILE__)
#if __has_builtin(__builtin_amdgcn_global_load_lds)
  __builtin_amdgcn_global_load_lds(
      (const __attribute__((address_space(1))) unsigned int*)g,
      (__attribute__((address_space(3))) unsigned int*)l, 16, 0, 0);
#else
  *(uint4*)l = *(const uint4*)g;
#endif
#else
  (void)g; (void)l;
#endif
}

// exp2 (v_exp_f32) if available; fallback numerically equivalent.
__device__ __forceinline__ float fexp2(float x) {
#if defined(__HIP_DEVICE_COMPILE__)
#if __has_builtin(__builtin_amdgcn_exp2f)
  return __builtin_amdgcn_exp2f(x);
#else
  return __expf(x * 0.6931471805599453f);
#endif
#else
  return x;
#endif
}

// packed f32x2 -> f16x2 convert (RTZ); builtin returns __fp16x2 — bit_cast to
// our _Float16-based half2v (round-7 compile failure was the implicit cast).
__device__ __forceinline__ half2v pk_f16(float a, float b) {
#if defined(__HIP_DEVICE_COMPILE__)
#if __has_builtin(__builtin_amdgcn_cvt_pkrtz)
  return __builtin_bit_cast(half2v, __builtin_amdgcn_cvt_pkrtz(a, b));
#else
  half2v r;
  r[0] = (_Float16)a;
  r[1] = (_Float16)b;
  return r;
#endif
#else
  half2v r;
  r[0] = (_Float16)a;
  r[1] = (_Float16)b;
  return r;
#endif
}

__device__ __forceinline__ unsigned short f2h(float f) {
  union { _Float16 h; unsigned short u; } v;
  v.h = (_Float16)f;
  return v.u;
}

// ---------- fp32 -> fp16 convert ----------
__global__ __launch_bounds__(256) void cvt_f32_f16(const float* __restrict__ in,
                                                   unsigned short* __restrict__ out, int n4) {
  int i = blockIdx.x * 256 + threadIdx.x;
  if (i >= n4) return;
  float4 v = ((const float4*)in)[i];
  uint2 o;
  o.x = (unsigned)f2h(v.x) | ((unsigned)f2h(v.y) << 16);
  o.y = (unsigned)f2h(v.z) | ((unsigned)f2h(v.w) << 16);
  ((uint2*)out)[i] = o;
}

// ---------- shared GEMM core: 256x128 tile, K=512, 512 threads (8 waves 4x2) ----------
// X rows come from two 128-row halves at element offsets xrow0/xrow1 (row-major,
// stride 512). XOR chunk swizzle: LDS slot (row r, chunk sc) holds global chunk
// sc^(r&7); reader of chunk c uses c^(r&7). Staging slots lane-contiguous.
#define GEMM_CORE(WGPTR)                                                               \
  for (int k0 = 0; k0 < 512; k0 += 64) {                                               \
    _Pragma("unroll") for (int rnd = 0; rnd < 4; ++rnd) {                              \
      const int slot = rnd * 512 + tid;                                                \
      const int r = slot >> 3;                                                         \
      const int c = (slot & 7) ^ (r & 7);                                              \
      const size_t src = ((r >> 7) ? xrow1 : xrow0) + (size_t)(r & 127) * 512 +        \
                         (size_t)(k0 + c * 8);                                         \
      gl_lds16(Xbase + src, &Xs[slot * 8]);                                            \
    }                                                                                  \
    _Pragma("unroll") for (int rnd = 0; rnd < 2; ++rnd) {                              \
      const int s2 = rnd * 512 + tid;                                                  \
      const int r = s2 >> 3;                                                           \
      const int c = (s2 & 7) ^ (r & 7);                                                \
      gl_lds16((WGPTR) + (size_t)r * 512 + k0 + c * 8, &Wt[s2 * 8]);                   \
    }                                                                                  \
    __syncthreads();                                                                   \
    _Pragma("unroll") for (int kk = 0; kk < 2; ++kk) {                                 \
      half8 af[4], bf[4];                                                              \
      const int ch = ((kk * 4 + grp) ^ (col & 7)) * 8;                                 \
      _Pragma("unroll") for (int i = 0; i < 4; ++i)                                    \
          af[i] = *(const half8*)&Xs[(wm + i * 16 + col) * 64 + ch];                   \
      _Pragma("unroll") for (int j = 0; j < 4; ++j)                                    \
          bf[j] = *(const half8*)&Wt[(wn + j * 16 + col) * 64 + ch];                   \
      _Pragma("unroll") for (int i = 0; i < 4; ++i)                                    \
          _Pragma("unroll") for (int j = 0; j < 4; ++j)                                \
              acc[i][j] = mfma16x16x32_f16(af[i], bf[j], acc[i][j]);                   \
    }                                                                                  \
    __syncthreads();                                                                   \
  }

// ---------- QKV projection GEMM: C = X @ W[widx]^T + b[widx], fp16 in/out ----------
// M-tile = 2 consecutive batches x one 128-row t-chunk (widx-uniform even for
// the chunk-split dispatch). grid (4 n-tiles, 48 m-tiles, 3 {q,k,v}).
__global__ __launch_bounds__(512) void gemm_qkv(
    const unsigned short* __restrict__ X,
    const unsigned short* __restrict__ Wq, const unsigned short* __restrict__ Wk,
    const unsigned short* __restrict__ Wv,
    const float* __restrict__ bq, const float* __restrict__ bk, const float* __restrict__ bv,
    unsigned short* __restrict__ Cq, unsigned short* __restrict__ Ck, unsigned short* __restrict__ Cv,
    int wsel_mode, int widx_fixed) {
  const int nt = blockIdx.x, mt = blockIdx.y, z = blockIdx.z;
  const unsigned short* W = (z == 0) ? Wq : ((z == 1) ? Wk : Wv);
  const float* bias = (z == 0) ? bq : ((z == 1) ? bk : bv);
  unsigned short* C = (z == 0) ? Cq : ((z == 1) ? Ck : Cv);
  const int cpart = mt % 3, bb = (mt / 3) * 2;
  const int widx = wsel_mode ? (1 + cpart) : widx_fixed;
  W += (size_t)widx * 512 * 512;
  bias += widx * 512;

  const size_t grow0 = (size_t)bb * 384 + cpart * 128;  // global row of local row 0
  const size_t grow1 = grow0 + 384;                     // of local row 128
  const size_t xrow0 = grow0 * 512, xrow1 = grow1 * 512;
  const unsigned short* Xbase = X;

  __shared__ __align__(16) unsigned short Xs[2048 * 8];  // 256x64 f16 (32 KB)
  __shared__ __align__(16) unsigned short Wt[1024 * 8];  // 128x64 f16 (16 KB)
  const int tid = threadIdx.x, lane = tid & 63, w = tid >> 6;
  const int col = lane & 15, grp = lane >> 4;
  const int wm = (w >> 1) * 64, wn = (w & 1) * 64;

  const float4v zero4 = {0.f, 0.f, 0.f, 0.f};
  float4v acc[4][4];
#pragma unroll
  for (int i = 0; i < 4; ++i)
#pragma unroll
    for (int j = 0; j < 4; ++j) acc[i][j] = zero4;

  GEMM_CORE(W + (size_t)nt * 128 * 512)

#pragma unroll
  for (int j = 0; j < 4; ++j) {
    const int n = nt * 128 + wn + j * 16 + col;
    const float bj = bias[n];
#pragma unroll
    for (int i = 0; i < 4; ++i)
#pragma unroll
      for (int r = 0; r < 4; ++r) {
        const int m = wm + i * 16 + grp * 4 + r;
        const size_t grow = ((m >> 7) ? grow1 : grow0) + (m & 127);
        C[grow * 512 + n] = f2h(acc[i][j][r] + bj);
      }
  }
}

// ---------- fusion GEMM: diff = Xdiff @ W^T ; out = tl2 + (tl1-tl2)*sigmoid(diff) ----------
__global__ __launch_bounds__(512) void gemm_fusion(
    const unsigned short* __restrict__ X, const unsigned short* __restrict__ Wf,
    const float* __restrict__ tl1, const float* __restrict__ tl2, float* __restrict__ outp) {
  const int nt = blockIdx.x, mt = blockIdx.y;
  const size_t grow0 = (size_t)mt * 256, grow1 = grow0 + 128;
  const size_t xrow0 = grow0 * 512, xrow1 = grow1 * 512;
  const unsigned short* Xbase = X;

  __shared__ __align__(16) unsigned short Xs[2048 * 8];
  __shared__ __align__(16) unsigned short Wt[1024 * 8];
  const int tid = threadIdx.x, lane = tid & 63, w = tid >> 6;
  const int col = lane & 15, grp = lane >> 4;
  const int wm = (w >> 1) * 64, wn = (w & 1) * 64;

  const float4v zero4 = {0.f, 0.f, 0.f, 0.f};
  float4v acc[4][4];
#pragma unroll
  for (int i = 0; i < 4; ++i)
#pragma unroll
    for (int j = 0; j < 4; ++j) acc[i][j] = zero4;

  GEMM_CORE(Wf + (size_t)nt * 128 * 512)

#pragma unroll
  for (int j = 0; j < 4; ++j) {
    const int n = nt * 128 + wn + j * 16 + col;
#pragma unroll
    for (int i = 0; i < 4; ++i)
#pragma unroll
      for (int r = 0; r < 4; ++r) {
        const int m = wm + i * 16 + grp * 4 + r;
        const size_t off = (((m >> 7) ? grow1 : grow0) + (m & 127)) * 512 + n;
        const float t1 = tl1[off], t2 = tl2[off];
        const float sg = 1.0f / (1.0f + __expf(-acc[i][j][r]));
        outp[off] = t2 + (t1 - t2) * sg;
      }
  }
}

// ---------- attention, single-S-pass, 512 threads per (b,h[,chunk]) ----------
// S[t,s] = sum_dd K[dd,t]*V[dd,s] (×temp); NB t-tiles per barrier: Z exchange
// once per group; P' = exp(S)/Z in fp16 (<=1), Q fed unscaled fp16 -> Q @ P'.
template <int T, int NB>
__global__ __launch_bounds__(512) void attn_kernel(
    const unsigned short* __restrict__ Qb, const unsigned short* __restrict__ Kb,
    const unsigned short* __restrict__ Vb, const float* __restrict__ temp_base,
    const float* add_src,  // no restrict: may alias outp (in-place tl2)
    float* outp, int chunk_elems,
    const float* __restrict__ tl1_src, unsigned short* __restrict__ diff_out) {
  constexpr int NT = T / 16;         // t-tiles
  constexpr int NSW = (T / 16) / 8;  // s-tiles per wave (8 waves split s)
  constexpr int SLAB = T * 32;
  const int h = blockIdx.x, b = blockIdx.y, cb = blockIdx.z;
  const int base = b * (384 * 512) + cb * chunk_elems + h * SLAB;
  const float tl2e = temp_base[cb * 16 + h] * 1.4426950408889634f;  // temp*log2(e)

  __shared__ __align__(16) unsigned short KVt[T][40];  // V then K, transposed [t][dd]
  __shared__ __align__(16) float Zp[2][NB][8][16];     // [parity][tile][wave][t]

  const int tid = threadIdx.x, lane = tid & 63, w = tid >> 6;
  const int col = lane & 15, grp = lane >> 4;

  // --- staging: column-gather transpose, conflict-free b128 LDS writes ---
  auto stage = [&](const unsigned short* src) {
    constexpr int ITER = (T * 4) / 512;
#pragma unroll
    for (int p = 0; p < ITER; ++p) {
      const int f = p * 512 + tid;
      const int t = f >> 2, blk = (f & 3) * 8;
      unsigned short tmp[8];
#pragma unroll
      for (int i = 0; i < 8; ++i) tmp[i] = src[(size_t)(blk + i) * T + t];
      *(uint4*)&KVt[t][blk] = *(const uint4*)tmp;
    }
  };

  stage(Vb + base);
  __syncthreads();
  half8 vfr[NSW];  // this wave's V fragments (s-strips w + si*8)
#pragma unroll
  for (int si = 0; si < NSW; ++si)
    vfr[si] = *(const half8*)&KVt[(w + si * 8) * 16 + col][grp * 8];
  __syncthreads();
  stage(Kb + base);  // reuse buffer for K
  __syncthreads();

  const float4v zero4 = {0.f, 0.f, 0.f, 0.f};
  const unsigned short* Qsl = Qb + base;
  float4v oacc[NSW][2];
#pragma unroll
  for (int si = 0; si < NSW; ++si) {
    oacc[si][0] = zero4;
    oacc[si][1] = zero4;
  }

  for (int g = 0; g < NT / NB; ++g) {
    const int par = g & 1;
    float pe[NB][NSW][4];
    // --- S + exp + in-wave Z partials for NB tiles ---
#pragma unroll
    for (int u = 0; u < NB; ++u) {
      const int tt = g * NB + u;
      half8 kf = *(const half8*)&KVt[tt * 16 + col][grp * 8];
      float z0 = 0.f, z1 = 0.f, z2 = 0.f, z3 = 0.f;
#pragma unroll
      for (int si = 0; si < NSW; ++si) {
        float4v s = mfma16x16x32_f16(kf, vfr[si], zero4);
        pe[u][si][0] = fexp2(s[0] * tl2e);
        pe[u][si][1] = fexp2(s[1] * tl2e);
        pe[u][si][2] = fexp2(s[2] * tl2e);
        pe[u][si][3] = fexp2(s[3] * tl2e);
        z0 += pe[u][si][0];
        z1 += pe[u][si][1];
        z2 += pe[u][si][2];
        z3 += pe[u][si][3];
      }
#pragma unroll
      for (int m = 1; m < 16; m <<= 1) {
        z0 += __shfl_xor(z0, m);
        z1 += __shfl_xor(z1, m);
        z2 += __shfl_xor(z2, m);
        z3 += __shfl_xor(z3, m);
      }
      if (col == 0) {
        float4v zv = {z0, z1, z2, z3};
        *(float4v*)&Zp[par][u][w][grp * 4] = zv;
      }
    }
    // Q fragments for all NB tiles (issued before barrier)
    half4v qa[NB][2];
#pragma unroll
    for (int u = 0; u < NB; ++u) {
      const int toff = (g * NB + u) * 16 + grp * 4;
      qa[u][0] = *(const half4v*)(Qsl + col * T + toff);
      qa[u][1] = *(const half4v*)(Qsl + (16 + col) * T + toff);
    }
    __syncthreads();
    // --- combine 8 wave partials, then PV ---
#pragma unroll
    for (int u = 0; u < NB; ++u) {
      float4v zs = zero4;
#pragma unroll
      for (int ww = 0; ww < 8; ++ww) zs += *(const float4v*)&Zp[par][u][ww][grp * 4];
      const float zi0 = 1.0f / zs[0], zi1 = 1.0f / zs[1], zi2 = 1.0f / zs[2],
                  zi3 = 1.0f / zs[3];
#pragma unroll
      for (int si = 0; si < NSW; ++si) {
        half2v lo = pk_f16(pe[u][si][0] * zi0, pe[u][si][1] * zi1);
        half2v hi = pk_f16(pe[u][si][2] * zi2, pe[u][si][3] * zi3);
        half4v pb = __builtin_shufflevector(lo, hi, 0, 1, 2, 3);
        oacc[si][0] = mfma16x16x16_f16(qa[u][0], pb, oacc[si][0]);
        oacc[si][1] = mfma16x16x16_f16(qa[u][1], pb, oacc[si][1]);
      }
    }
  }

  // --- epilogue ---
#pragma unroll
  for (int si = 0; si < NSW; ++si) {
    const int s = (w + si * 8) * 16 + col;
#pragma unroll
    for (int m0 = 0; m0 < 2; ++m0) {
#pragma unroll
      for (int r = 0; r < 4; ++r) {
        const int dd = m0 * 16 + grp * 4 + r;
        const int off = base + dd * T + s;
        float v = oacc[si][m0][r];
        if (add_src) v += add_src[off];
        outp[off] = v;
        if (diff_out) diff_out[off] = f2h(tl1_src[off] - v);
      }
    }
  }
}

// ---------- layernorm over rows of 512 -> fp16 ----------
__global__ __launch_bounds__(256) void ln_kernel(const float* __restrict__ xin,
                                                 const float* __restrict__ g,
                                                 const float* __restrict__ bb,
                                                 unsigned short* __restrict__ y) {
  const int row = blockIdx.x * 4 + (threadIdx.x >> 6);
  const int lane = threadIdx.x & 63;
  const float* xr = xin + (size_t)row * 512;
  float4 v0 = *(const float4*)&xr[lane * 8];
  float4 v1 = *(const float4*)&xr[lane * 8 + 4];
  float s = v0.x + v0.y + v0.z + v0.w + v1.x + v1.y + v1.z + v1.w;
  float q = v0.x * v0.x + v0.y * v0.y + v0.z * v0.z + v0.w * v0.w +
            v1.x * v1.x + v1.y * v1.y + v1.z * v1.z + v1.w * v1.w;
#pragma unroll
  for (int m = 1; m < 64; m <<= 1) {
    s += __shfl_xor(s, m);
    q += __shfl_xor(q, m);
  }
  const float mean = s * (1.0f / 512.0f);
  const float var = q * (1.0f / 512.0f) - mean * mean;
  const float rs = rsqrtf(var + 1e-5f);
  float4 g0 = *(const float4*)&g[lane * 8];
  float4 g1 = *(const float4*)&g[lane * 8 + 4];
  float4 b0 = *(const float4*)&bb[lane * 8];
  float4 b1 = *(const float4*)&bb[lane * 8 + 4];
  uint4 o;
  o.x = (unsigned)f2h((v0.x - mean) * rs * g0.x + b0.x) |
        ((unsigned)f2h((v0.y - mean) * rs * g0.y + b0.y) << 16);
  o.y = (unsigned)f2h((v0.z - mean) * rs * g0.z + b0.z) |
        ((unsigned)f2h((v0.w - mean) * rs * g0.w + b0.w) << 16);
  o.z = (unsigned)f2h((v1.x - mean) * rs * g1.x + b1.x) |
        ((unsigned)f2h((v1.y - mean) * rs * g1.y + b1.y) << 16);
  o.w = (unsigned)f2h((v1.z - mean) * rs * g1.z + b1.z) |
        ((unsigned)f2h((v1.w - mean) * rs * g1.w + b1.w) << 16);
  *(uint4*)&y[(size_t)row * 512 + lane * 8] = o;
}

// ---------- launch ----------
extern "C" void kernel_launch(void* const* d_in, const int* in_sizes, int n_in,
                              void* d_out, int out_size, void* d_ws, size_t ws_size,
                              hipStream_t stream) {
  const float* x = (const float*)d_in[0];
  const float* qw = (const float*)d_in[1];
  const float* qb = (const float*)d_in[2];
  const float* kw = (const float*)d_in[3];
  const float* kb = (const float*)d_in[4];
  const float* vw = (const float*)d_in[5];
  const float* vb = (const float*)d_in[6];
  const float* temp = (const float*)d_in[7];
  const float* ln_g = (const float*)d_in[8];
  const float* ln_b = (const float*)d_in[9];
  const float* fus_w = (const float*)d_in[10];
  // fus_b (d_in[11]) cancels in the 2-way softmax; num_heads (d_in[12]) fixed at 16
  float* out = (float*)d_out;

  const size_t NE = (size_t)32 * 384 * 512;  // 6291456
  const size_t WE = (size_t)5 * 512 * 512;   // 1310720

  char* p = (char*)d_ws;
  auto alloc = [&](size_t bytes) {
    char* r = p;
    p += (bytes + 255) & ~(size_t)255;
    return r;
  };
  unsigned short* xb = (unsigned short*)alloc(NE * 2);
  unsigned short* wqb = (unsigned short*)alloc(WE * 2);
  unsigned short* wkb = (unsigned short*)alloc(WE * 2);
  unsigned short* wvb = (unsigned short*)alloc(WE * 2);
  unsigned short* fwb = (unsigned short*)alloc((size_t)512 * 512 * 2);
  unsigned short* Qb = (unsigned short*)alloc(NE * 2);
  unsigned short* Kb = (unsigned short*)alloc(NE * 2);
  unsigned short* Vb = (unsigned short*)alloc(NE * 2);
  float* xres = (float*)alloc(NE * 4);  // x_ , later tl2 (in place)
  float* tl1 = (float*)alloc(NE * 4);
  unsigned short* yb = (unsigned short*)alloc(NE * 2);  // LN output, later diff (fp16)

  // converts
  cvt_f32_f16<<<(int)((NE / 4 + 255) / 256), 256, 0, stream>>>(x, xb, (int)(NE / 4));
  cvt_f32_f16<<<(int)((WE / 4 + 255) / 256), 256, 0, stream>>>(qw, wqb, (int)(WE / 4));
  cvt_f32_f16<<<(int)((WE / 4 + 255) / 256), 256, 0, stream>>>(kw, wkb, (int)(WE / 4));
  cvt_f32_f16<<<(int)((WE / 4 + 255) / 256), 256, 0, stream>>>(vw, wvb, (int)(WE / 4));
  cvt_f32_f16<<<256, 256, 0, stream>>>(fus_w, fwb, 512 * 512 / 4);

  // block 0 projections + attention -> x_ (xres)
  gemm_qkv<<<dim3(4, 48, 3), 512, 0, stream>>>(xb, wqb, wkb, wvb, qb, kb, vb, Qb, Kb, Vb, 0, 0);
  attn_kernel<384, 4><<<dim3(16, 32, 1), 512, 0, stream>>>(Qb, Kb, Vb, temp, nullptr, xres, 0,
                                                           nullptr, nullptr);
  // blocks 1-3 (chunked) projections + attention -> tl1 = concat + x_
  gemm_qkv<<<dim3(4, 48, 3), 512, 0, stream>>>(xb, wqb, wkb, wvb, qb, kb, vb, Qb, Kb, Vb, 1, 0);
  attn_kernel<128, 2><<<dim3(16, 32, 3), 512, 0, stream>>>(Qb, Kb, Vb, temp + 16, xres, tl1,
                                                           128 * 512, nullptr, nullptr);
  // layernorm -> y (fp16)
  ln_kernel<<<12288 / 4, 256, 0, stream>>>(tl1, ln_g, ln_b, yb);
  // block 4 projections + attention -> tl2 = out + x_ (in-place into xres), diff -> yb
  gemm_qkv<<<dim3(4, 48, 3), 512, 0, stream>>>(yb, wqb, wkb, wvb, qb, kb, vb, Qb, Kb, Vb, 0, 4);
  attn_kernel<384, 4><<<dim3(16, 32, 1), 512, 0, stream>>>(Qb, Kb, Vb, temp + 64, xres, xres, 0,
                                                           tl1, yb);
  // fusion: out = tl2 + (tl1-tl2)*sigmoid((tl1-tl2)@fus_w^T)
  gemm_fusion<<<dim3(4, 48), 512, 0, stream>>>(yb, fwb, tl1, xres, out);

  (void)in_sizes; (void)n_in; (void)out_size; (void)ws_size;
}